// Round 10
// baseline (100.803 us; speedup 1.0000x reference)
//
#include <hip/hip_runtime.h>
#include <math.h>

typedef __attribute__((ext_vector_type(8))) short short8;
typedef __attribute__((ext_vector_type(4))) float f32x4;

#if defined(__has_builtin)
#if __has_builtin(__builtin_amdgcn_global_load_lds)
#define HAVE_GLL 1
#endif
#if __has_builtin(__builtin_amdgcn_sqrtf)
#define FSQRT(x) __builtin_amdgcn_sqrtf(x)
#endif
#if __has_builtin(__builtin_amdgcn_sched_barrier)
#define SCHED_PIN() __builtin_amdgcn_sched_barrier(0)
#endif
#endif
#ifndef HAVE_GLL
#define HAVE_GLL 0
#endif
#ifndef FSQRT
#define FSQRT(x) sqrtf(x)
#endif
#ifndef SCHED_PIN
#define SCHED_PIN()
#endif

__device__ __forceinline__ unsigned short f2bf(float f) {
    unsigned int x = __float_as_uint(f);
    unsigned int r = (x + 0x7fffu + ((x >> 16) & 1u)) >> 16;   // RNE
    return (unsigned short)r;
}

// ws layout (bytes):
//  [0..256)             uint hist[64]
//  [512..67584)         double partials[nL][4]  (se, sd2, set, pad)
//  [67584..+4N)         float sq[N]
//  [67584+4N..+8N)      int ci[N]
//  [67584+8N.. )        ushort xh[N*D]  (bf16 copy, if ws permits)

__global__ void rowstats_kernel(const float* __restrict__ x, const int* __restrict__ idx,
                                float* __restrict__ sq, int* __restrict__ ci,
                                unsigned int* __restrict__ hist, unsigned short* __restrict__ xh,
                                int N, int D, int doCvt) {
    int wave0 = (blockIdx.x * blockDim.x + threadIdx.x) >> 6;
    int lane  = threadIdx.x & 63;
    int nw    = (gridDim.x * blockDim.x) >> 6;
    for (int row = wave0; row < N; row += nw) {
        const float* rp = x + (size_t)row * D;
        float s = 0.f;
        for (int c = lane * 4; c < D; c += 256) {
            float4 v = *reinterpret_cast<const float4*>(rp + c);
            s = fmaf(v.x, v.x, s); s = fmaf(v.y, v.y, s);
            s = fmaf(v.z, v.z, s); s = fmaf(v.w, v.w, s);
            if (doCvt) {
                ushort4 h;
                h.x = f2bf(v.x); h.y = f2bf(v.y); h.z = f2bf(v.z); h.w = f2bf(v.w);
                *reinterpret_cast<ushort4*>(xh + (size_t)row * D + c) = h;
            }
        }
        #pragma unroll
        for (int o = 32; o > 0; o >>= 1) s += __shfl_down(s, o, 64);
        if (lane == 0) {
            sq[row] = s;
            int v = idx[row]; if (v > 63) v = 63;
            ci[row] = v;
            atomicAdd(&hist[v], 1u);
        }
    }
}

__device__ __forceinline__ void tri_decode(int L, int NB, int chunks, int doSwz, int& bi, int& bj) {
    if (doSwz) { int xcd = L & 7, pos = L >> 3; L = xcd * chunks + pos; }
    float disc = (float)((2 * NB + 1) * (2 * NB + 1) - 8 * L);
    int b = (int)(((float)(2 * NB + 1) - sqrtf(disc)) * 0.5f);
    if (b < 0) b = 0; if (b > NB - 1) b = NB - 1;
    while (b + 1 <= NB - 1 && ((b + 1) * NB - ((b + 1) * b) / 2) <= L) ++b;
    while (b > 0 && (b * NB - (b * (b - 1)) / 2) > L) --b;
    bi = b; bj = b + (L - (b * NB - (b * (b - 1)) / 2));
}

// ================= 256x256-tile phase-split kernel (8 waves) =================
// LDS: 3 K-tile buffers of 32KB (BK=32), frag-order 1KB segments:
//   buffer (t%3) at (t%3)*32768; seg S in [0,32): A: S=mblk(0..15); B: S=16+nblk.
//   Within seg: lane*16 holds row blk*16+(lane&15), k-octet (lane>>4)*8 -> one
//   ds_read_b128 at seg+lane*16 IS the MFMA fragment.  [r7-proven layout]
// Total 102784 B — inside the 128 KiB per-WG cap (135552 was rejected in r9).
#define P256_LDS_BYTES 102784
#define P256_TBL    98304
#define P256_SQA    98560
#define P256_SQB    99584
#define P256_CAA   100608
#define P256_CBB   101632
#define P256_RED   102656

__global__ __launch_bounds__(512, 1) void pair256_kernel(
        const unsigned short* __restrict__ xh, const float* __restrict__ table,
        const float* __restrict__ sq, const int* __restrict__ ci,
        int D, int NB, int chunks, int doSwz, double* __restrict__ partials) {
#if HAVE_GLL
    extern __shared__ char dyn[];
    float* tbl = (float*)(dyn + P256_TBL);
    float* sqA = (float*)(dyn + P256_SQA);
    float* sqB = (float*)(dyn + P256_SQB);
    int*   caA = (int*)(dyn + P256_CAA);
    int*   cbB = (int*)(dyn + P256_CBB);
    float* red = (float*)(dyn + P256_RED);

    int bi, bj;
    tri_decode(blockIdx.x, NB, chunks, doSwz, bi, bj);

    const int tid = threadIdx.x;
    const int w = tid >> 6, lane = tid & 63;
    const int wr = w >> 2, wc = w & 3;          // 2M x 4N wave grid; wave tile 128x64
    const int l15 = lane & 15, koct = lane >> 4;

    // aux loads first (compiler drains their vmcnt before the ds_writes)
    if (tid < 64) tbl[tid] = table[tid];        // Toeplitz: T[u][v] = table[|u-v|]
    if (tid < 256) { sqA[tid] = sq[bi * 256 + tid]; caA[tid] = ci[bi * 256 + tid]; }
    else { int t2 = tid - 256; sqB[t2] = sq[bj * 256 + t2]; cbB[t2] = ci[bj * 256 + t2]; }

    // staging: wave w owns segs [w*4, w*4+4); STAGE2 issues 2 of them (j=0,1)
    const int rowoff = ((w >= 4) ? bj : bi) * 256 + l15;
    auto STAGE2 = [&](int t, int bufi, int j) {
        #pragma unroll
        for (int q = 0; q < 2; ++q) {
            int S = (w << 2) + (j << 1) + q;
            int blk = S & 15;
            const unsigned short* g = xh + (size_t)(rowoff + blk * 16) * D + t * 32 + koct * 8;
            char* dst = dyn + (bufi << 15) + (S << 10);   // + lane*16 by HW
            __builtin_amdgcn_global_load_lds(
                (__attribute__((address_space(1))) void*)(void*)g,
                (__attribute__((address_space(3))) void*)dst, 16, 0, 0);
        }
    };

    f32x4 acc[8][4];
    #pragma unroll
    for (int a = 0; a < 8; ++a)
        #pragma unroll
        for (int b = 0; b < 4; ++b) acc[a][b] = (f32x4){0.f, 0.f, 0.f, 0.f};

    // prologue: stage tiles 0,1 (8 gll/wave); wait own tile-0 (4 newest in flight)
    STAGE2(0, 0, 0); STAGE2(0, 0, 1);
    STAGE2(1, 1, 0); STAGE2(1, 1, 1);
    asm volatile("s_waitcnt vmcnt(4) lgkmcnt(0)" ::: "memory");
    __builtin_amdgcn_s_barrier();
    SCHED_PIN();

    short8 bReg[4];

    auto PHASE0 = [&](int bufi, int st, int sbufi, bool doStage) {
        const int boff = bufi << 15;
        #pragma unroll
        for (int n = 0; n < 4; ++n)
            bReg[n] = *reinterpret_cast<const short8*>(dyn + boff + 16384 + (((wc << 2) | n) << 10) + (lane << 4));
        short8 a_[4];
        #pragma unroll
        for (int m = 0; m < 4; ++m)
            a_[m] = *reinterpret_cast<const short8*>(dyn + boff + (((wr << 3) + m) << 10) + (lane << 4));
        if (doStage) STAGE2(st, sbufi, 0);
        __builtin_amdgcn_s_barrier();
        __builtin_amdgcn_s_setprio(1);
        #pragma unroll
        for (int m = 0; m < 4; ++m)
            #pragma unroll
            for (int n = 0; n < 4; ++n)
                acc[m][n] = __builtin_amdgcn_mfma_f32_16x16x32_bf16(a_[m], bReg[n], acc[m][n], 0, 0, 0);
        __builtin_amdgcn_s_setprio(0);
    };
    auto PHASE1 = [&](int bufi, int st, int sbufi, bool doStage) {
        const int boff = bufi << 15;
        short8 a_[4];
        #pragma unroll
        for (int m = 0; m < 4; ++m)
            a_[m] = *reinterpret_cast<const short8*>(dyn + boff + (((wr << 3) + 4 + m) << 10) + (lane << 4));
        if (doStage) STAGE2(st, sbufi, 1);
        __builtin_amdgcn_s_barrier();
        __builtin_amdgcn_s_setprio(1);
        #pragma unroll
        for (int m = 0; m < 4; ++m)
            #pragma unroll
            for (int n = 0; n < 4; ++n)
                acc[4 + m][n] = __builtin_amdgcn_mfma_f32_16x16x32_bf16(a_[m], bReg[n], acc[4 + m][n], 0, 0, 0);
        __builtin_amdgcn_s_setprio(0);
    };

    // K pipeline: 8 tiles of BK=32, depth-3. Counted vmcnt, never 0 until drain.
    #define TILE_S(t, bufi, sbufi) \
        PHASE0(bufi, (t) + 2, sbufi, true); \
        PHASE1(bufi, (t) + 2, sbufi, true); \
        asm volatile("s_waitcnt vmcnt(4)" ::: "memory"); \
        __builtin_amdgcn_s_barrier(); \
        SCHED_PIN();

    TILE_S(0, 0, 2)
    TILE_S(1, 1, 0)
    TILE_S(2, 2, 1)
    TILE_S(3, 0, 2)
    TILE_S(4, 1, 0)
    TILE_S(5, 2, 1)
    PHASE0(0, 0, 0, false); PHASE1(0, 0, 0, false);   // tile 6 in buf 0
    asm volatile("s_waitcnt vmcnt(0)" ::: "memory");
    __builtin_amdgcn_s_barrier();
    SCHED_PIN();
    PHASE0(1, 0, 0, false); PHASE1(1, 0, 0, false);   // tile 7 in buf 1
    __syncthreads();
    #undef TILE_S

    // ---- fused epilogue: row = wr*128 + mm*16 + koct*4 + rg; col = wc*64 + n*16 + l15
    float sb[4]; int cb[4];
    #pragma unroll
    for (int n = 0; n < 4; ++n) {
        int c = wc * 64 + n * 16 + l15;
        sb[n] = sqB[c]; cb[n] = cbB[c];
    }
    float se = 0.f, sd2 = 0.f, setv = 0.f;
    const bool diag = (bi == bj);
    #pragma unroll
    for (int mm = 0; mm < 8; ++mm) {
        #pragma unroll
        for (int rg = 0; rg < 4; ++rg) {
            int rr = wr * 128 + mm * 16 + koct * 4 + rg;
            float sa_ = sqA[rr]; int ca_ = caA[rr];
            #pragma unroll
            for (int n = 0; n < 4; ++n) {
                float d2 = fmaf(-2.f, acc[mm][n][rg], sa_ + sb[n]);
                d2 = fmaxf(d2, 0.f);
                if (diag && rr == wc * 64 + n * 16 + l15) d2 = 0.f;
                float e = FSQRT(d2);
                int delta = ca_ - cb[n]; if (delta < 0) delta = -delta;
                float t = tbl[delta];
                se += e; sd2 += d2; setv = fmaf(e, t, setv);
            }
        }
    }
    #pragma unroll
    for (int o = 32; o > 0; o >>= 1) {
        se  += __shfl_down(se, o, 64);
        sd2 += __shfl_down(sd2, o, 64);
        setv += __shfl_down(setv, o, 64);
    }
    if (lane == 0) { red[w * 3 + 0] = se; red[w * 3 + 1] = sd2; red[w * 3 + 2] = setv; }
    __syncthreads();
    if (tid == 0) {
        double wgt = diag ? 1.0 : 2.0;
        double S0 = 0, S1 = 0, S2 = 0;
        #pragma unroll
        for (int i = 0; i < 8; ++i) {
            S0 += (double)red[i * 3 + 0]; S1 += (double)red[i * 3 + 1]; S2 += (double)red[i * 3 + 2];
        }
        double* p = partials + (size_t)blockIdx.x * 4;
        p[0] = wgt * S0; p[1] = wgt * S1; p[2] = wgt * S2;
    }
#endif
}

// ================= fallback: r7-proven 128x128 staged kernel =================
template<bool DIAG>
__device__ __forceinline__ void epilogue128(const f32x4 (&acc)[4][4],
                                            const float* sqA, const float* sqB,
                                            const int* caA, const int* cbB, const float* tbl,
                                            float* red, int w, int lane, int wr, int wc,
                                            double* partials, int pidx) {
    const int l15 = lane & 15;
    const int rbase = wr * 64, cbase = wc * 64;
    const int rsub = (lane >> 4) << 2;
    float sb[4]; int cb[4];
    #pragma unroll
    for (int fn = 0; fn < 4; ++fn) {
        int c = cbase + fn * 16 + l15;
        sb[fn] = sqB[c]; cb[fn] = cbB[c];
    }
    float se = 0.f, sd2 = 0.f, setv = 0.f;
    #pragma unroll
    for (int fm = 0; fm < 4; ++fm)
        #pragma unroll
        for (int rg = 0; rg < 4; ++rg) {
            int r = rbase + fm * 16 + rsub + rg;
            float sa_ = sqA[r]; int ca_ = caA[r];
            #pragma unroll
            for (int fn = 0; fn < 4; ++fn) {
                float d2 = fmaf(-2.f, acc[fm][fn][rg], sa_ + sb[fn]);
                d2 = fmaxf(d2, 0.f);
                if (DIAG) { if (r == cbase + fn * 16 + l15) d2 = 0.f; }
                float e = FSQRT(d2);
                int delta = ca_ - cb[fn]; if (delta < 0) delta = -delta;
                float t = tbl[delta];
                se += e; sd2 += d2; setv = fmaf(e, t, setv);
            }
        }
    #pragma unroll
    for (int o = 32; o > 0; o >>= 1) {
        se  += __shfl_down(se, o, 64);
        sd2 += __shfl_down(sd2, o, 64);
        setv += __shfl_down(setv, o, 64);
    }
    if (lane == 0) { red[w * 3 + 0] = se; red[w * 3 + 1] = sd2; red[w * 3 + 2] = setv; }
    __syncthreads();
    if (w == 0 && lane == 0) {
        double wgt = DIAG ? 1.0 : 2.0;
        double S0 = 0, S1 = 0, S2 = 0;
        #pragma unroll
        for (int i = 0; i < 4; ++i) {
            S0 += (double)red[i * 3 + 0]; S1 += (double)red[i * 3 + 1]; S2 += (double)red[i * 3 + 2];
        }
        double* p = partials + (size_t)pidx * 4;
        p[0] = wgt * S0; p[1] = wgt * S1; p[2] = wgt * S2;
    }
}

template<bool PRE>
__global__ void pair_kernel(const float* __restrict__ x, const unsigned short* __restrict__ xh,
                            const float* __restrict__ table,
                            const float* __restrict__ sq, const int* __restrict__ ci,
                            int D, int NB, int chunks, int doSwz,
                            double* __restrict__ partials) {
    int bi, bj;
    tri_decode(blockIdx.x, NB, chunks, doSwz, bi, bj);

    __shared__ char ldsbuf[32768];
    __shared__ float sqA[128], sqB[128], tbl[64];
    __shared__ int   caA[128], cbB[128];
    __shared__ float red[12];

    const int tid = threadIdx.x;
    const int w = tid >> 6, lane = tid & 63;
    const int wr = w >> 1, wc = w & 1;
    const int l15 = lane & 15, koct = lane >> 4;

    if (tid < 64) tbl[tid] = table[tid];
    if (tid < 128) { sqA[tid] = sq[bi * 128 + tid]; caA[tid] = ci[bi * 128 + tid]; }
    else { int t2 = tid - 128; sqB[t2] = sq[bj * 128 + t2]; cbB[t2] = ci[bj * 128 + t2]; }
    __syncthreads();

    f32x4 acc[4][4];
    #pragma unroll
    for (int a = 0; a < 4; ++a)
        #pragma unroll
        for (int b = 0; b < 4; ++b) acc[a][b] = (f32x4){0.f, 0.f, 0.f, 0.f};

    const size_t aoff = (size_t)(bi * 128 + wr * 64 + l15) * D + koct * 8;
    const size_t boff = (size_t)(bj * 128 + wc * 64 + l15) * D + koct * 8;

    bool staged = false;
#if HAVE_GLL
    if (PRE && ((D & 63) == 0)) {
        staged = true;
        const unsigned short* gpan = (w >= 2) ? (xh + (size_t)bj * 128 * D)
                                              : (xh + (size_t)bi * 128 * D);
        const int kcw = w & 1;
        char* ldsw = ldsbuf + ((w >= 2) ? 16384 : 0) + kcw * 8192;
        const size_t gk = (size_t)(kcw * 32 + koct * 8) + (size_t)l15 * D;
        auto STAGE = [&](int ks) {
            const unsigned short* g0 = gpan + gk + ks * 64;
            #pragma unroll
            for (int i = 0; i < 8; ++i) {
                __builtin_amdgcn_global_load_lds(
                    (__attribute__((address_space(1))) void*)(void*)(g0 + (size_t)i * 16 * D),
                    (__attribute__((address_space(3))) void*)(ldsw + i * 1024),
                    16, 0, 0);
            }
        };
        const int nks = D >> 6;
        STAGE(0);
        for (int ks = 0; ks < nks; ++ks) {
            __syncthreads();
            #pragma unroll
            for (int kc = 0; kc < 2; ++kc) {
                short8 a[4], b[4];
                #pragma unroll
                for (int m = 0; m < 4; ++m)
                    a[m] = *reinterpret_cast<const short8*>(ldsbuf + (kc * 8 + wr * 4 + m) * 1024 + lane * 16);
                #pragma unroll
                for (int n = 0; n < 4; ++n)
                    b[n] = *reinterpret_cast<const short8*>(ldsbuf + 16384 + (kc * 8 + wc * 4 + n) * 1024 + lane * 16);
                #pragma unroll
                for (int fm = 0; fm < 4; ++fm)
                    #pragma unroll
                    for (int fn = 0; fn < 4; ++fn)
                        acc[fm][fn] = __builtin_amdgcn_mfma_f32_16x16x32_bf16(a[fm], b[fn], acc[fm][fn], 0, 0, 0);
            }
            if (ks + 1 < nks) { __syncthreads(); STAGE(ks + 1); }
        }
    }
#endif
    if (!staged) {
        const float* pa = x + aoff;
        const unsigned short* ha = xh + aoff;
        const float* pb = x + boff;
        const unsigned short* hb = xh + boff;
        const size_t rs = (size_t)16 * D;
        for (int k = 0; k < D; k += 32) {
            short8 af[4], bfv[4];
            if (PRE) {
                #pragma unroll
                for (int m = 0; m < 4; ++m) af[m]  = *reinterpret_cast<const short8*>(ha + m * rs + k);
                #pragma unroll
                for (int n = 0; n < 4; ++n) bfv[n] = *reinterpret_cast<const short8*>(hb + n * rs + k);
            } else {
                #pragma unroll
                for (int m = 0; m < 4; ++m) {
                    float4 f0 = *reinterpret_cast<const float4*>(pa + m * rs + k);
                    float4 f1 = *reinterpret_cast<const float4*>(pa + m * rs + k + 4);
                    short8 v;
                    v[0]=(short)f2bf(f0.x); v[1]=(short)f2bf(f0.y); v[2]=(short)f2bf(f0.z); v[3]=(short)f2bf(f0.w);
                    v[4]=(short)f2bf(f1.x); v[5]=(short)f2bf(f1.y); v[6]=(short)f2bf(f1.z); v[7]=(short)f2bf(f1.w);
                    af[m] = v;
                }
                #pragma unroll
                for (int n = 0; n < 4; ++n) {
                    float4 f0 = *reinterpret_cast<const float4*>(pb + n * rs + k);
                    float4 f1 = *reinterpret_cast<const float4*>(pb + n * rs + k + 4);
                    short8 v;
                    v[0]=(short)f2bf(f0.x); v[1]=(short)f2bf(f0.y); v[2]=(short)f2bf(f0.z); v[3]=(short)f2bf(f0.w);
                    v[4]=(short)f2bf(f1.x); v[5]=(short)f2bf(f1.y); v[6]=(short)f2bf(f1.z); v[7]=(short)f2bf(f1.w);
                    bfv[n] = v;
                }
            }
            #pragma unroll
            for (int fm = 0; fm < 4; ++fm)
                #pragma unroll
                for (int fn = 0; fn < 4; ++fn)
                    acc[fm][fn] = __builtin_amdgcn_mfma_f32_16x16x32_bf16(af[fm], bfv[fn], acc[fm][fn], 0, 0, 0);
        }
    }

    if (bi == bj) epilogue128<true >(acc, sqA, sqB, caA, cbB, tbl, red, w, lane, wr, wc, partials, blockIdx.x);
    else          epilogue128<false>(acc, sqA, sqB, caA, cbB, tbl, red, w, lane, wr, wc, partials, blockIdx.x);
}

__global__ void finalize_kernel(const double* __restrict__ partials, int nL,
                                const unsigned int* __restrict__ hist,
                                const float* __restrict__ table, int tdim,
                                float* __restrict__ out, long long n) {
    __shared__ unsigned int h[64];
    __shared__ double red[4][5];
    const int tid = threadIdx.x;     // 256 threads
    if (tid < 64) h[tid] = hist[tid];
    __syncthreads();

    double se = 0, sd2 = 0, setv = 0;
    for (int i = tid; i < nL; i += 256) {
        const double* p = partials + (size_t)i * 4;
        se += p[0]; sd2 += p[1]; setv += p[2];
    }
    double st = 0, stt = 0;
    for (int c = tid; c < 4096; c += 256) {
        int u = c >> 6, v = c & 63;
        double t = (double)table[u * tdim + v];
        double hh = (double)h[u] * (double)h[v];
        st += hh * t; stt += hh * t * t;
    }
    #pragma unroll
    for (int o = 32; o > 0; o >>= 1) {
        se += __shfl_down(se, o, 64);
        sd2 += __shfl_down(sd2, o, 64);
        setv += __shfl_down(setv, o, 64);
        st += __shfl_down(st, o, 64);
        stt += __shfl_down(stt, o, 64);
    }
    int w = tid >> 6;
    if ((tid & 63) == 0) { red[w][0] = se; red[w][1] = sd2; red[w][2] = setv; red[w][3] = st; red[w][4] = stt; }
    __syncthreads();
    if (tid == 0) {
        double S[5] = {0, 0, 0, 0, 0};
        #pragma unroll
        for (int i = 0; i < 4; ++i)
            #pragma unroll
            for (int q = 0; q < 5; ++q) S[q] += red[i][q];
        double nn = (double)n;
        // Pearson corr is scale-invariant: the /(max+eps) normalization is a no-op
        double cet = S[2] - S[0] * S[3] / nn;
        double cee = S[1] - S[0] * S[0] / nn;
        double ctt = S[4] - S[3] * S[3] / nn;
        double corr = cet / (sqrt(cee * ctt) + 1e-10);
        out[0] = (float)(1.0 - corr);
    }
}

extern "C" void kernel_launch(void* const* d_in, const int* in_sizes, int n_in,
                              void* d_out, int out_size, void* d_ws, size_t ws_size,
                              hipStream_t stream) {
    const float* x     = (const float*)d_in[0];
    const int*   idx   = (const int*)d_in[1];
    const float* table = (const float*)d_in[2];

    const int N = in_sizes[1];              // 8192
    const int D = in_sizes[0] / N;          // 256
    int tdim = 1;
    while (tdim * tdim < in_sizes[2]) ++tdim;   // 81

    char* ws = (char*)d_ws;
    unsigned int*   hist     = (unsigned int*)ws;
    double*         partials = (double*)(ws + 512);
    float*          sqv      = (float*)(ws + 67584);
    int*            civ      = (int*)(ws + 67584 + (size_t)N * 4);
    unsigned short* xh       = (unsigned short*)(ws + 67584 + (size_t)N * 8);

    size_t need = 67584 + (size_t)N * 8 + (size_t)N * D * 2;
    const bool pre = (ws_size >= need);

    hipMemsetAsync(d_ws, 0, 256, stream);
    rowstats_kernel<<<dim3(512), 256, 0, stream>>>(x, idx, sqv, civ, hist, xh, N, D, pre ? 1 : 0);

    bool p256 = pre && (N % 256 == 0) && (D == 256) && HAVE_GLL;
    if (p256) {
        hipError_t e = hipFuncSetAttribute((const void*)pair256_kernel,
                                           hipFuncAttributeMaxDynamicSharedMemorySize,
                                           P256_LDS_BYTES);
        p256 = (e == hipSuccess);
    }

    if (p256) {
        const int NB2 = N / 256;
        const int nL2 = NB2 * (NB2 + 1) / 2;         // 528
        const int doSwz2 = (nL2 % 8 == 0) ? 1 : 0;
        const int chunks2 = nL2 / 8;
        pair256_kernel<<<dim3(nL2), 512, P256_LDS_BYTES, stream>>>(
            xh, table, sqv, civ, D, NB2, chunks2, doSwz2, partials);
        finalize_kernel<<<1, 256, 0, stream>>>(partials, nL2, hist, table, tdim,
                                               (float*)d_out, (long long)N * (long long)N);
    } else {
        const int NB = N / 128;
        const int nL = NB * (NB + 1) / 2;            // 2080
        const int doSwz = (nL % 8 == 0) ? 1 : 0;
        const int chunks = nL / 8;
        if (pre)
            pair_kernel<true><<<dim3(nL), 256, 0, stream>>>(x, xh, table, sqv, civ, D, NB, chunks, doSwz, partials);
        else
            pair_kernel<false><<<dim3(nL), 256, 0, stream>>>(x, xh, table, sqv, civ, D, NB, chunks, doSwz, partials);
        finalize_kernel<<<1, 256, 0, stream>>>(partials, nL, hist, table, tdim,
                                               (float*)d_out, (long long)N * (long long)N);
    }
}

// Round 11
// 72.900 us; speedup vs baseline: 1.3828x; 1.3828x over previous
//
#include <hip/hip_runtime.h>
#include <math.h>

typedef __attribute__((ext_vector_type(8))) short short8;
typedef __attribute__((ext_vector_type(4))) float f32x4;

#if defined(__has_builtin)
#if __has_builtin(__builtin_amdgcn_global_load_lds)
#define HAVE_GLL 1
#endif
#if __has_builtin(__builtin_amdgcn_sqrtf)
#define FSQRT(x) __builtin_amdgcn_sqrtf(x)
#endif
#if __has_builtin(__builtin_amdgcn_sched_barrier)
#define SCHED_PIN() __builtin_amdgcn_sched_barrier(0)
#endif
#endif
#ifndef HAVE_GLL
#define HAVE_GLL 0
#endif
#ifndef FSQRT
#define FSQRT(x) sqrtf(x)
#endif
#ifndef SCHED_PIN
#define SCHED_PIN()
#endif

__device__ __forceinline__ unsigned short f2bf(float f) {
    unsigned int x = __float_as_uint(f);
    unsigned int r = (x + 0x7fffu + ((x >> 16) & 1u)) >> 16;   // RNE
    return (unsigned short)r;
}

// ws layout (bytes):
//  [512..67584)         double partials[nL][4]  (se, sd2, set, pad)
//  [67584..+4N)         float sq[N]
//  [67584+4N..+8N)      int ci[N]  (clamped indices)
//  [67584+8N.. )        ushort xh[N*D]  (bf16 copy, if ws permits)

__global__ void rowstats_kernel(const float* __restrict__ x, const int* __restrict__ idx,
                                float* __restrict__ sq, int* __restrict__ ci,
                                unsigned short* __restrict__ xh,
                                int N, int D, int doCvt) {
    int wave0 = (blockIdx.x * blockDim.x + threadIdx.x) >> 6;
    int lane  = threadIdx.x & 63;
    int nw    = (gridDim.x * blockDim.x) >> 6;
    for (int row = wave0; row < N; row += nw) {
        const float* rp = x + (size_t)row * D;
        float s = 0.f;
        for (int c = lane * 4; c < D; c += 256) {
            float4 v = *reinterpret_cast<const float4*>(rp + c);
            s = fmaf(v.x, v.x, s); s = fmaf(v.y, v.y, s);
            s = fmaf(v.z, v.z, s); s = fmaf(v.w, v.w, s);
            if (doCvt) {
                ushort4 h;
                h.x = f2bf(v.x); h.y = f2bf(v.y); h.z = f2bf(v.z); h.w = f2bf(v.w);
                *reinterpret_cast<ushort4*>(xh + (size_t)row * D + c) = h;
            }
        }
        #pragma unroll
        for (int o = 32; o > 0; o >>= 1) s += __shfl_down(s, o, 64);
        if (lane == 0) {
            sq[row] = s;
            int v = idx[row]; if (v > 63) v = 63;
            ci[row] = v;
        }
    }
}

__device__ __forceinline__ void tri_decode(int L, int NB, int chunks, int doSwz, int& bi, int& bj) {
    if (doSwz) { int xcd = L & 7, pos = L >> 3; L = xcd * chunks + pos; }
    float disc = (float)((2 * NB + 1) * (2 * NB + 1) - 8 * L);
    int b = (int)(((float)(2 * NB + 1) - sqrtf(disc)) * 0.5f);
    if (b < 0) b = 0; if (b > NB - 1) b = NB - 1;
    while (b + 1 <= NB - 1 && ((b + 1) * NB - ((b + 1) * b) / 2) <= L) ++b;
    while (b > 0 && (b * NB - (b * (b - 1)) / 2) > L) --b;
    bi = b; bj = b + (L - (b * NB - (b * (b - 1)) / 2));
}

// ================= 256x256-tile phase-split kernel (8 waves) =================
// LDS: 3 K-tile buffers of 32KB (BK=32), frag-order 1KB segments:
//   buffer at bufi*32768; seg S in [0,32): A: S=mblk(0..15); B: S=16+nblk.
//   Within seg: lane*16 holds row blk*16+(lane&15), k-octet (lane>>4)*8 -> one
//   ds_read_b128 at seg+lane*16 IS the MFMA fragment.  [r7-proven layout]
#define P256_LDS_BYTES 102784
#define P256_TBL    98304
#define P256_SQA    98560
#define P256_SQB    99584
#define P256_CAA   100608
#define P256_CBB   101632
#define P256_RED   102656

__global__ __launch_bounds__(512, 1) void pair256_kernel(
        const unsigned short* __restrict__ xh, const float* __restrict__ table,
        const float* __restrict__ sq, const int* __restrict__ ci,
        int D, int NB, int chunks, int doSwz, double* __restrict__ partials) {
    extern __shared__ char dyn[];
    float* tbl = (float*)(dyn + P256_TBL);
    float* sqA = (float*)(dyn + P256_SQA);
    float* sqB = (float*)(dyn + P256_SQB);
    int*   caA = (int*)(dyn + P256_CAA);
    int*   cbB = (int*)(dyn + P256_CBB);
    float* red = (float*)(dyn + P256_RED);

    int bi, bj;
    tri_decode(blockIdx.x, NB, chunks, doSwz, bi, bj);

    const int tid = threadIdx.x;
    const int w = tid >> 6, lane = tid & 63;
    const int wr = w >> 2, wc = w & 3;          // 2M x 4N wave grid; wave tile 128x64
    const int l15 = lane & 15, koct = lane >> 4;

    f32x4 acc[8][4];
    #pragma unroll
    for (int a = 0; a < 8; ++a)
        #pragma unroll
        for (int b = 0; b < 4; ++b) acc[a][b] = (f32x4){0.f, 0.f, 0.f, 0.f};

#if HAVE_GLL
    // aux loads first (their vmcnt drains inside the prologue wait)
    if (tid < 64) tbl[tid] = table[tid];        // Toeplitz: T[u][v] = table[|u-v|]
    if (tid < 256) { sqA[tid] = sq[bi * 256 + tid]; caA[tid] = ci[bi * 256 + tid]; }
    else { int t2 = tid - 256; sqB[t2] = sq[bj * 256 + t2]; cbB[t2] = ci[bj * 256 + t2]; }

    // staging: wave w owns segs [w*4, w*4+4); STAGE2 issues 2 of them (j=0,1)
    const int rowoff = ((w >= 4) ? bj : bi) * 256 + l15;
    auto STAGE2 = [&](int t, int bufi, int j) {
        #pragma unroll
        for (int q = 0; q < 2; ++q) {
            int S = (w << 2) + (j << 1) + q;
            int blk = S & 15;
            const unsigned short* g = xh + (size_t)(rowoff + blk * 16) * D + t * 32 + koct * 8;
            char* dst = dyn + (bufi << 15) + (S << 10);   // + lane*16 by HW
            __builtin_amdgcn_global_load_lds(
                (__attribute__((address_space(1))) void*)(void*)g,
                (__attribute__((address_space(3))) void*)dst, 16, 0, 0);
        }
    };

    // prologue: stage tiles 0,1 (8 gll/wave); wait tile-0 (4 newest still in flight)
    STAGE2(0, 0, 0); STAGE2(0, 0, 1);
    STAGE2(1, 1, 0); STAGE2(1, 1, 1);
    asm volatile("s_waitcnt vmcnt(4) lgkmcnt(0)" ::: "memory");
    __builtin_amdgcn_s_barrier();
    SCHED_PIN();

    short8 bReg[4];

    auto PHASE0 = [&](int bufi, int st, int sbufi, bool doStage) {
        const int boff = bufi << 15;
        #pragma unroll
        for (int n = 0; n < 4; ++n)
            bReg[n] = *reinterpret_cast<const short8*>(dyn + boff + 16384 + (((wc << 2) | n) << 10) + (lane << 4));
        short8 a_[4];
        #pragma unroll
        for (int m = 0; m < 4; ++m)
            a_[m] = *reinterpret_cast<const short8*>(dyn + boff + (((wr << 3) + m) << 10) + (lane << 4));
        if (doStage) STAGE2(st, sbufi, 0);
        __builtin_amdgcn_s_barrier();
        __builtin_amdgcn_s_setprio(1);
        #pragma unroll
        for (int m = 0; m < 4; ++m)
            #pragma unroll
            for (int n = 0; n < 4; ++n)
                acc[m][n] = __builtin_amdgcn_mfma_f32_16x16x32_bf16(a_[m], bReg[n], acc[m][n], 0, 0, 0);
        __builtin_amdgcn_s_setprio(0);
    };
    auto PHASE1 = [&](int bufi, int st, int sbufi, bool doStage) {
        const int boff = bufi << 15;
        short8 a_[4];
        #pragma unroll
        for (int m = 0; m < 4; ++m)
            a_[m] = *reinterpret_cast<const short8*>(dyn + boff + (((wr << 3) + 4 + m) << 10) + (lane << 4));
        if (doStage) STAGE2(st, sbufi, 1);
        __builtin_amdgcn_s_barrier();
        __builtin_amdgcn_s_setprio(1);
        #pragma unroll
        for (int m = 0; m < 4; ++m)
            #pragma unroll
            for (int n = 0; n < 4; ++n)
                acc[4 + m][n] = __builtin_amdgcn_mfma_f32_16x16x32_bf16(a_[m], bReg[n], acc[4 + m][n], 0, 0, 0);
        __builtin_amdgcn_s_setprio(0);
    };

    // K pipeline: 8 tiles of BK=32, depth-3. Counted vmcnt, never 0 until drain.
    #define TILE_S(t, bufi, sbufi) \
        PHASE0(bufi, (t) + 2, sbufi, true); \
        PHASE1(bufi, (t) + 2, sbufi, true); \
        asm volatile("s_waitcnt vmcnt(4)" ::: "memory"); \
        __builtin_amdgcn_s_barrier(); \
        SCHED_PIN();

    TILE_S(0, 0, 2)
    TILE_S(1, 1, 0)
    TILE_S(2, 2, 1)
    TILE_S(3, 0, 2)
    TILE_S(4, 1, 0)
    TILE_S(5, 2, 1)
    PHASE0(0, 0, 0, false); PHASE1(0, 0, 0, false);   // tile 6 in buf 0
    asm volatile("s_waitcnt vmcnt(0)" ::: "memory");
    __builtin_amdgcn_s_barrier();
    SCHED_PIN();
    PHASE0(1, 0, 0, false); PHASE1(1, 0, 0, false);   // tile 7 in buf 1
    __syncthreads();
    #undef TILE_S
#else
    // safety net for toolchains without global_load_lds: direct frag loads
    if (tid < 64) tbl[tid] = table[tid];
    if (tid < 256) { sqA[tid] = sq[bi * 256 + tid]; caA[tid] = ci[bi * 256 + tid]; }
    else { int t2 = tid - 256; sqB[t2] = sq[bj * 256 + t2]; cbB[t2] = ci[bj * 256 + t2]; }
    __syncthreads();
    const size_t rsa = (size_t)(bi * 256 + wr * 128 + l15) * D + koct * 8;
    const size_t rsb = (size_t)(bj * 256 + wc * 64 + l15) * D + koct * 8;
    for (int k = 0; k < D; k += 32) {
        short8 bv[4];
        #pragma unroll
        for (int n = 0; n < 4; ++n)
            bv[n] = *reinterpret_cast<const short8*>(xh + rsb + (size_t)(n * 16) * D + k);
        #pragma unroll
        for (int mm = 0; mm < 8; ++mm) {
            short8 av = *reinterpret_cast<const short8*>(xh + rsa + (size_t)(mm * 16) * D + k);
            #pragma unroll
            for (int n = 0; n < 4; ++n)
                acc[mm][n] = __builtin_amdgcn_mfma_f32_16x16x32_bf16(av, bv[n], acc[mm][n], 0, 0, 0);
        }
    }
#endif

    // ---- fused epilogue: row = wr*128 + mm*16 + koct*4 + rg; col = wc*64 + n*16 + l15
    float sb[4]; int cb[4];
    #pragma unroll
    for (int n = 0; n < 4; ++n) {
        int c = wc * 64 + n * 16 + l15;
        sb[n] = sqB[c]; cb[n] = cbB[c];
    }
    float se = 0.f, sd2 = 0.f, setv = 0.f;
    const bool diag = (bi == bj);
    #pragma unroll
    for (int mm = 0; mm < 8; ++mm) {
        #pragma unroll
        for (int rg = 0; rg < 4; ++rg) {
            int rr = wr * 128 + mm * 16 + koct * 4 + rg;
            float sa_ = sqA[rr]; int ca_ = caA[rr];
            #pragma unroll
            for (int n = 0; n < 4; ++n) {
                float d2 = fmaf(-2.f, acc[mm][n][rg], sa_ + sb[n]);
                d2 = fmaxf(d2, 0.f);
                if (diag && rr == wc * 64 + n * 16 + l15) d2 = 0.f;
                float e = FSQRT(d2);
                int delta = ca_ - cb[n]; if (delta < 0) delta = -delta;
                float t = tbl[delta];
                se += e; sd2 += d2; setv = fmaf(e, t, setv);
            }
        }
    }
    #pragma unroll
    for (int o = 32; o > 0; o >>= 1) {
        se  += __shfl_down(se, o, 64);
        sd2 += __shfl_down(sd2, o, 64);
        setv += __shfl_down(setv, o, 64);
    }
    if (lane == 0) { red[w * 3 + 0] = se; red[w * 3 + 1] = sd2; red[w * 3 + 2] = setv; }
    __syncthreads();
    if (tid == 0) {
        double wgt = diag ? 1.0 : 2.0;
        double S0 = 0, S1 = 0, S2 = 0;
        #pragma unroll
        for (int i = 0; i < 8; ++i) {
            S0 += (double)red[i * 3 + 0]; S1 += (double)red[i * 3 + 1]; S2 += (double)red[i * 3 + 2];
        }
        double* p = partials + (size_t)blockIdx.x * 4;
        p[0] = wgt * S0; p[1] = wgt * S1; p[2] = wgt * S2;
    }
}

// ================= fallback: r7-proven 128x128 staged kernel =================
template<bool DIAG>
__device__ __forceinline__ void epilogue128(const f32x4 (&acc)[4][4],
                                            const float* sqA, const float* sqB,
                                            const int* caA, const int* cbB, const float* tbl,
                                            float* red, int w, int lane, int wr, int wc,
                                            double* partials, int pidx) {
    const int l15 = lane & 15;
    const int rbase = wr * 64, cbase = wc * 64;
    const int rsub = (lane >> 4) << 2;
    float sb[4]; int cb[4];
    #pragma unroll
    for (int fn = 0; fn < 4; ++fn) {
        int c = cbase + fn * 16 + l15;
        sb[fn] = sqB[c]; cb[fn] = cbB[c];
    }
    float se = 0.f, sd2 = 0.f, setv = 0.f;
    #pragma unroll
    for (int fm = 0; fm < 4; ++fm)
        #pragma unroll
        for (int rg = 0; rg < 4; ++rg) {
            int r = rbase + fm * 16 + rsub + rg;
            float sa_ = sqA[r]; int ca_ = caA[r];
            #pragma unroll
            for (int fn = 0; fn < 4; ++fn) {
                float d2 = fmaf(-2.f, acc[fm][fn][rg], sa_ + sb[fn]);
                d2 = fmaxf(d2, 0.f);
                if (DIAG) { if (r == cbase + fn * 16 + l15) d2 = 0.f; }
                float e = FSQRT(d2);
                int delta = ca_ - cb[fn]; if (delta < 0) delta = -delta;
                float t = tbl[delta];
                se += e; sd2 += d2; setv = fmaf(e, t, setv);
            }
        }
    #pragma unroll
    for (int o = 32; o > 0; o >>= 1) {
        se  += __shfl_down(se, o, 64);
        sd2 += __shfl_down(sd2, o, 64);
        setv += __shfl_down(setv, o, 64);
    }
    if (lane == 0) { red[w * 3 + 0] = se; red[w * 3 + 1] = sd2; red[w * 3 + 2] = setv; }
    __syncthreads();
    if (w == 0 && lane == 0) {
        double wgt = DIAG ? 1.0 : 2.0;
        double S0 = 0, S1 = 0, S2 = 0;
        #pragma unroll
        for (int i = 0; i < 4; ++i) {
            S0 += (double)red[i * 3 + 0]; S1 += (double)red[i * 3 + 1]; S2 += (double)red[i * 3 + 2];
        }
        double* p = partials + (size_t)pidx * 4;
        p[0] = wgt * S0; p[1] = wgt * S1; p[2] = wgt * S2;
    }
}

template<bool PRE>
__global__ void pair_kernel(const float* __restrict__ x, const unsigned short* __restrict__ xh,
                            const float* __restrict__ table,
                            const float* __restrict__ sq, const int* __restrict__ ci,
                            int D, int NB, int chunks, int doSwz,
                            double* __restrict__ partials) {
    int bi, bj;
    tri_decode(blockIdx.x, NB, chunks, doSwz, bi, bj);

    __shared__ char ldsbuf[32768];
    __shared__ float sqA[128], sqB[128], tbl[64];
    __shared__ int   caA[128], cbB[128];
    __shared__ float red[12];

    const int tid = threadIdx.x;
    const int w = tid >> 6, lane = tid & 63;
    const int wr = w >> 1, wc = w & 1;
    const int l15 = lane & 15, koct = lane >> 4;

    if (tid < 64) tbl[tid] = table[tid];
    if (tid < 128) { sqA[tid] = sq[bi * 128 + tid]; caA[tid] = ci[bi * 128 + tid]; }
    else { int t2 = tid - 128; sqB[t2] = sq[bj * 128 + t2]; cbB[t2] = ci[bj * 128 + t2]; }
    __syncthreads();

    f32x4 acc[4][4];
    #pragma unroll
    for (int a = 0; a < 4; ++a)
        #pragma unroll
        for (int b = 0; b < 4; ++b) acc[a][b] = (f32x4){0.f, 0.f, 0.f, 0.f};

    const size_t aoff = (size_t)(bi * 128 + wr * 64 + l15) * D + koct * 8;
    const size_t boff = (size_t)(bj * 128 + wc * 64 + l15) * D + koct * 8;

    bool staged = false;
#if HAVE_GLL
    if (PRE && ((D & 63) == 0)) {
        staged = true;
        const unsigned short* gpan = (w >= 2) ? (xh + (size_t)bj * 128 * D)
                                              : (xh + (size_t)bi * 128 * D);
        const int kcw = w & 1;
        char* ldsw = ldsbuf + ((w >= 2) ? 16384 : 0) + kcw * 8192;
        const size_t gk = (size_t)(kcw * 32 + koct * 8) + (size_t)l15 * D;
        auto STAGE = [&](int ks) {
            const unsigned short* g0 = gpan + gk + ks * 64;
            #pragma unroll
            for (int i = 0; i < 8; ++i) {
                __builtin_amdgcn_global_load_lds(
                    (__attribute__((address_space(1))) void*)(void*)(g0 + (size_t)i * 16 * D),
                    (__attribute__((address_space(3))) void*)(ldsw + i * 1024),
                    16, 0, 0);
            }
        };
        const int nks = D >> 6;
        STAGE(0);
        for (int ks = 0; ks < nks; ++ks) {
            __syncthreads();
            #pragma unroll
            for (int kc = 0; kc < 2; ++kc) {
                short8 a[4], b[4];
                #pragma unroll
                for (int m = 0; m < 4; ++m)
                    a[m] = *reinterpret_cast<const short8*>(ldsbuf + (kc * 8 + wr * 4 + m) * 1024 + lane * 16);
                #pragma unroll
                for (int n = 0; n < 4; ++n)
                    b[n] = *reinterpret_cast<const short8*>(ldsbuf + 16384 + (kc * 8 + wc * 4 + n) * 1024 + lane * 16);
                #pragma unroll
                for (int fm = 0; fm < 4; ++fm)
                    #pragma unroll
                    for (int fn = 0; fn < 4; ++fn)
                        acc[fm][fn] = __builtin_amdgcn_mfma_f32_16x16x32_bf16(a[fm], b[fn], acc[fm][fn], 0, 0, 0);
            }
            if (ks + 1 < nks) { __syncthreads(); STAGE(ks + 1); }
        }
    }
#endif
    if (!staged) {
        const float* pa = x + aoff;
        const unsigned short* ha = xh + aoff;
        const float* pb = x + boff;
        const unsigned short* hb = xh + boff;
        const size_t rs = (size_t)16 * D;
        for (int k = 0; k < D; k += 32) {
            short8 af[4], bfv[4];
            if (PRE) {
                #pragma unroll
                for (int m = 0; m < 4; ++m) af[m]  = *reinterpret_cast<const short8*>(ha + m * rs + k);
                #pragma unroll
                for (int n = 0; n < 4; ++n) bfv[n] = *reinterpret_cast<const short8*>(hb + n * rs + k);
            } else {
                #pragma unroll
                for (int m = 0; m < 4; ++m) {
                    float4 f0 = *reinterpret_cast<const float4*>(pa + m * rs + k);
                    float4 f1 = *reinterpret_cast<const float4*>(pa + m * rs + k + 4);
                    short8 v;
                    v[0]=(short)f2bf(f0.x); v[1]=(short)f2bf(f0.y); v[2]=(short)f2bf(f0.z); v[3]=(short)f2bf(f0.w);
                    v[4]=(short)f2bf(f1.x); v[5]=(short)f2bf(f1.y); v[6]=(short)f2bf(f1.z); v[7]=(short)f2bf(f1.w);
                    af[m] = v;
                }
                #pragma unroll
                for (int n = 0; n < 4; ++n) {
                    float4 f0 = *reinterpret_cast<const float4*>(pb + n * rs + k);
                    float4 f1 = *reinterpret_cast<const float4*>(pb + n * rs + k + 4);
                    short8 v;
                    v[0]=(short)f2bf(f0.x); v[1]=(short)f2bf(f0.y); v[2]=(short)f2bf(f0.z); v[3]=(short)f2bf(f0.w);
                    v[4]=(short)f2bf(f1.x); v[5]=(short)f2bf(f1.y); v[6]=(short)f2bf(f1.z); v[7]=(short)f2bf(f1.w);
                    bfv[n] = v;
                }
            }
            #pragma unroll
            for (int fm = 0; fm < 4; ++fm)
                #pragma unroll
                for (int fn = 0; fn < 4; ++fn)
                    acc[fm][fn] = __builtin_amdgcn_mfma_f32_16x16x32_bf16(af[fm], bfv[fn], acc[fm][fn], 0, 0, 0);
        }
    }

    if (bi == bj) epilogue128<true >(acc, sqA, sqB, caA, cbB, tbl, red, w, lane, wr, wc, partials, blockIdx.x);
    else          epilogue128<false>(acc, sqA, sqB, caA, cbB, tbl, red, w, lane, wr, wc, partials, blockIdx.x);
}

__global__ void finalize_kernel(const double* __restrict__ partials, int nL,
                                const int* __restrict__ civ, int N,
                                const float* __restrict__ table, int tdim,
                                float* __restrict__ out) {
    __shared__ unsigned int h[64];
    __shared__ double red[4][5];
    const int tid = threadIdx.x;     // 256 threads
    if (tid < 64) h[tid] = 0u;
    __syncthreads();
    for (int i = tid; i < N; i += 256) atomicAdd(&h[civ[i]], 1u);   // LDS histogram
    __syncthreads();

    double se = 0, sd2 = 0, setv = 0;
    for (int i = tid; i < nL; i += 256) {
        const double* p = partials + (size_t)i * 4;
        se += p[0]; sd2 += p[1]; setv += p[2];
    }
    double st = 0, stt = 0;
    for (int c = tid; c < 4096; c += 256) {
        int u = c >> 6, v = c & 63;
        double t = (double)table[u * tdim + v];
        double hh = (double)h[u] * (double)h[v];
        st += hh * t; stt += hh * t * t;
    }
    #pragma unroll
    for (int o = 32; o > 0; o >>= 1) {
        se += __shfl_down(se, o, 64);
        sd2 += __shfl_down(sd2, o, 64);
        setv += __shfl_down(setv, o, 64);
        st += __shfl_down(st, o, 64);
        stt += __shfl_down(stt, o, 64);
    }
    int w = tid >> 6;
    if ((tid & 63) == 0) { red[w][0] = se; red[w][1] = sd2; red[w][2] = setv; red[w][3] = st; red[w][4] = stt; }
    __syncthreads();
    if (tid == 0) {
        double S[5] = {0, 0, 0, 0, 0};
        #pragma unroll
        for (int i = 0; i < 4; ++i)
            #pragma unroll
            for (int q = 0; q < 5; ++q) S[q] += red[i][q];
        double nn = (double)N * (double)N;
        // Pearson corr is scale-invariant: the /(max+eps) normalization is a no-op
        double cet = S[2] - S[0] * S[3] / nn;
        double cee = S[1] - S[0] * S[0] / nn;
        double ctt = S[4] - S[3] * S[3] / nn;
        double corr = cet / (sqrt(cee * ctt) + 1e-10);
        out[0] = (float)(1.0 - corr);
    }
}

extern "C" void kernel_launch(void* const* d_in, const int* in_sizes, int n_in,
                              void* d_out, int out_size, void* d_ws, size_t ws_size,
                              hipStream_t stream) {
    const float* x     = (const float*)d_in[0];
    const int*   idx   = (const int*)d_in[1];
    const float* table = (const float*)d_in[2];

    const int N = in_sizes[1];              // 8192
    const int D = in_sizes[0] / N;          // 256
    int tdim = 1;
    while (tdim * tdim < in_sizes[2]) ++tdim;   // 81

    char* ws = (char*)d_ws;
    double*         partials = (double*)(ws + 512);
    float*          sqv      = (float*)(ws + 67584);
    int*            civ      = (int*)(ws + 67584 + (size_t)N * 4);
    unsigned short* xh       = (unsigned short*)(ws + 67584 + (size_t)N * 8);

    size_t need = 67584 + (size_t)N * 8 + (size_t)N * D * 2;
    const bool pre = (ws_size >= need);

    rowstats_kernel<<<dim3(512), 256, 0, stream>>>(x, idx, sqv, civ, xh, N, D, pre ? 1 : 0);

    // NOTE: host-side gate must NOT reference HAVE_GLL (it is 0 in the host
    // compile pass even when the device pass has the builtin — r9/r10 bug).
    bool p256 = pre && (N % 256 == 0) && (D == 256);
    if (p256) {
        hipError_t e = hipFuncSetAttribute((const void*)pair256_kernel,
                                           hipFuncAttributeMaxDynamicSharedMemorySize,
                                           P256_LDS_BYTES);
        p256 = (e == hipSuccess);
    }

    if (p256) {
        const int NB2 = N / 256;
        const int nL2 = NB2 * (NB2 + 1) / 2;         // 528
        const int doSwz2 = (nL2 % 8 == 0) ? 1 : 0;
        const int chunks2 = nL2 / 8;
        pair256_kernel<<<dim3(nL2), 512, P256_LDS_BYTES, stream>>>(
            xh, table, sqv, civ, D, NB2, chunks2, doSwz2, partials);
        finalize_kernel<<<1, 256, 0, stream>>>(partials, nL2, civ, N, table, tdim, (float*)d_out);
    } else {
        const int NB = N / 128;
        const int nL = NB * (NB + 1) / 2;            // 2080
        const int doSwz = (nL % 8 == 0) ? 1 : 0;
        const int chunks = nL / 8;
        if (pre)
            pair_kernel<true><<<dim3(nL), 256, 0, stream>>>(x, xh, table, sqv, civ, D, NB, chunks, doSwz, partials);
        else
            pair_kernel<false><<<dim3(nL), 256, 0, stream>>>(x, xh, table, sqv, civ, D, NB, chunks, doSwz, partials);
        finalize_kernel<<<1, 256, 0, stream>>>(partials, nL, civ, N, table, tdim, (float*)d_out);
    }
}

// Round 12
// 66.141 us; speedup vs baseline: 1.5241x; 1.1022x over previous
//
#include <hip/hip_runtime.h>
#include <math.h>

typedef __attribute__((ext_vector_type(8))) short short8;
typedef __attribute__((ext_vector_type(4))) float f32x4;

#if defined(__has_builtin)
#if __has_builtin(__builtin_amdgcn_global_load_lds)
#define HAVE_GLL 1
#endif
#if __has_builtin(__builtin_amdgcn_sqrtf)
#define FSQRT(x) __builtin_amdgcn_sqrtf(x)
#endif
#if __has_builtin(__builtin_amdgcn_sched_barrier)
#define SCHED_PIN() __builtin_amdgcn_sched_barrier(0)
#endif
#endif
#ifndef HAVE_GLL
#define HAVE_GLL 0
#endif
#ifndef FSQRT
#define FSQRT(x) sqrtf(x)
#endif
#ifndef SCHED_PIN
#define SCHED_PIN()
#endif

__device__ __forceinline__ unsigned short f2bf(float f) {
    unsigned int x = __float_as_uint(f);
    unsigned int r = (x + 0x7fffu + ((x >> 16) & 1u)) >> 16;   // RNE
    return (unsigned short)r;
}

// ws layout (bytes):
//  [512..67584)         double partials[nL][4]  (se, sd2, set, pad)
//  [67584..+4N)         float sq[N]
//  [67584+4N..+8N)      int ci[N]  (clamped indices)
//  [67584+8N.. )        ushort xh[N*D]  (bf16 copy, if ws permits)

__global__ void rowstats_kernel(const float* __restrict__ x, const int* __restrict__ idx,
                                float* __restrict__ sq, int* __restrict__ ci,
                                unsigned short* __restrict__ xh,
                                int N, int D, int doCvt) {
    int wave0 = (blockIdx.x * blockDim.x + threadIdx.x) >> 6;
    int lane  = threadIdx.x & 63;
    int nw    = (gridDim.x * blockDim.x) >> 6;
    for (int row = wave0; row < N; row += nw) {
        const float* rp = x + (size_t)row * D;
        float s = 0.f;
        for (int c = lane * 4; c < D; c += 256) {
            float4 v = *reinterpret_cast<const float4*>(rp + c);
            s = fmaf(v.x, v.x, s); s = fmaf(v.y, v.y, s);
            s = fmaf(v.z, v.z, s); s = fmaf(v.w, v.w, s);
            if (doCvt) {
                ushort4 h;
                h.x = f2bf(v.x); h.y = f2bf(v.y); h.z = f2bf(v.z); h.w = f2bf(v.w);
                *reinterpret_cast<ushort4*>(xh + (size_t)row * D + c) = h;
            }
        }
        #pragma unroll
        for (int o = 32; o > 0; o >>= 1) s += __shfl_down(s, o, 64);
        if (lane == 0) {
            sq[row] = s;
            int v = idx[row]; if (v > 63) v = 63;
            ci[row] = v;
        }
    }
}

__device__ __forceinline__ void tri_decode(int L, int NB, int chunks, int doSwz, int& bi, int& bj) {
    if (doSwz) { int xcd = L & 7, pos = L >> 3; L = xcd * chunks + pos; }
    float disc = (float)((2 * NB + 1) * (2 * NB + 1) - 8 * L);
    int b = (int)(((float)(2 * NB + 1) - sqrtf(disc)) * 0.5f);
    if (b < 0) b = 0; if (b > NB - 1) b = NB - 1;
    while (b + 1 <= NB - 1 && ((b + 1) * NB - ((b + 1) * b) / 2) <= L) ++b;
    while (b > 0 && (b * NB - (b * (b - 1)) / 2) > L) --b;
    bi = b; bj = b + (L - (b * NB - (b * (b - 1)) / 2));
}

// ---- shared epilogue: distances + Toeplitz gather + 3 accumulators + reduce ----
template<bool DIAG>
__device__ __forceinline__ void epilogue128(const f32x4 (&acc)[4][4],
                                            const float* sqA, const float* sqB,
                                            const int* caA, const int* cbB, const float* tbl,
                                            float* red, int w, int lane, int wr, int wc,
                                            double* partials, int pidx) {
    const int l15 = lane & 15;
    const int rbase = wr * 64, cbase = wc * 64;
    const int rsub = (lane >> 4) << 2;
    float sb[4]; int cb[4];
    #pragma unroll
    for (int fn = 0; fn < 4; ++fn) {
        int c = cbase + fn * 16 + l15;
        sb[fn] = sqB[c]; cb[fn] = cbB[c];
    }
    float se = 0.f, sd2 = 0.f, setv = 0.f;
    #pragma unroll
    for (int fm = 0; fm < 4; ++fm)
        #pragma unroll
        for (int rg = 0; rg < 4; ++rg) {
            int r = rbase + fm * 16 + rsub + rg;
            float sa_ = sqA[r]; int ca_ = caA[r];
            #pragma unroll
            for (int fn = 0; fn < 4; ++fn) {
                float d2 = fmaf(-2.f, acc[fm][fn][rg], sa_ + sb[fn]);
                d2 = fmaxf(d2, 0.f);
                if (DIAG) { if (r == cbase + fn * 16 + l15) d2 = 0.f; }
                float e = FSQRT(d2);
                int delta = ca_ - cb[fn]; if (delta < 0) delta = -delta;
                float t = tbl[delta];
                se += e; sd2 += d2; setv = fmaf(e, t, setv);
            }
        }
    #pragma unroll
    for (int o = 32; o > 0; o >>= 1) {
        se  += __shfl_down(se, o, 64);
        sd2 += __shfl_down(sd2, o, 64);
        setv += __shfl_down(setv, o, 64);
    }
    if (lane == 0) { red[w * 3 + 0] = se; red[w * 3 + 1] = sd2; red[w * 3 + 2] = setv; }
    __syncthreads();
    if (w == 0 && lane == 0) {
        double wgt = DIAG ? 1.0 : 2.0;
        double S0 = 0, S1 = 0, S2 = 0;
        #pragma unroll
        for (int i = 0; i < 4; ++i) {
            S0 += (double)red[i * 3 + 0]; S1 += (double)red[i * 3 + 1]; S2 += (double)red[i * 3 + 2];
        }
        double* p = partials + (size_t)pidx * 4;
        p[0] = wgt * S0; p[1] = wgt * S1; p[2] = wgt * S2;
    }
}

// ======= 128x128 tile, BK=32, 3-buffer counted-vmcnt pipeline (D=256) =======
// LDS buffer b at b*16384: 16 segs of 1KB; seg s<8: A blk=s; s>=8: B blk=s-8.
// Within seg: lane*16 holds row blk*16+(lane&15), k-octet (lane>>4) -> one
// ds_read_b128 at seg*1024+lane*16 IS the MFMA fragment (r7-proven layout).
__global__ __launch_bounds__(256, 2) void pair128p_kernel(
        const unsigned short* __restrict__ xh, const float* __restrict__ table,
        const float* __restrict__ sq, const int* __restrict__ ci,
        int NB, int chunks, int doSwz, double* __restrict__ partials) {
#if HAVE_GLL
    constexpr int D = 256;
    __shared__ char lds[49152];          // 3 x 16KB K-tile buffers
    __shared__ float sqA[128], sqB[128], tbl[64];
    __shared__ int   caA[128], cbB[128];
    __shared__ float red[12];

    int bi, bj;
    tri_decode(blockIdx.x, NB, chunks, doSwz, bi, bj);

    const int tid = threadIdx.x;
    const int w = tid >> 6, lane = tid & 63;
    const int wr = w >> 1, wc = w & 1;
    const int l15 = lane & 15, koct = lane >> 4;

    // aux loads FIRST (oldest in vmcnt queue -> drained by prologue vmcnt(4))
    if (tid < 64) tbl[tid] = table[tid];              // Toeplitz: T[u][v]=table[|u-v|]
    if (tid < 128) { sqA[tid] = sq[bi * 128 + tid]; caA[tid] = ci[bi * 128 + tid]; }
    else { int t2 = tid - 128; sqB[t2] = sq[bj * 128 + t2]; cbB[t2] = ci[bj * 128 + t2]; }

    // wave w stages 4 segs/tile: w<2 -> A blks (w&1)*4+q ; w>=2 -> B blks
    const unsigned short* gpan = xh + (size_t)((w >= 2 ? bj : bi) * 128 + l15) * D + koct * 8;
    const int segbase = (w >= 2 ? 8 : 0) + (w & 1) * 4;
    auto STAGE4 = [&](int t, int bufi) {
        #pragma unroll
        for (int q = 0; q < 4; ++q) {
            int blk = (w & 1) * 4 + q;
            const unsigned short* g = gpan + (size_t)(blk * 16) * D + t * 32;
            char* dst = lds + (bufi << 14) + ((segbase + q) << 10);   // +lane*16 by HW
            __builtin_amdgcn_global_load_lds(
                (__attribute__((address_space(1))) void*)(void*)g,
                (__attribute__((address_space(3))) void*)dst, 16, 0, 0);
        }
    };

    f32x4 acc[4][4];
    #pragma unroll
    for (int a = 0; a < 4; ++a)
        #pragma unroll
        for (int b = 0; b < 4; ++b) acc[a][b] = (f32x4){0.f, 0.f, 0.f, 0.f};

    // prologue: stage tiles 0,1; wait tile0 + aux (4 newest = tile1 still in flight)
    STAGE4(0, 0);
    STAGE4(1, 1);
    asm volatile("s_waitcnt vmcnt(4) lgkmcnt(0)" ::: "memory");
    __builtin_amdgcn_s_barrier();
    SCHED_PIN();

    // one K-tile: stage (t+2) early, 8 ds_read + 16 MFMA, counted wait, barrier
    #define K_TILE(bufi, sbufi, doStage, st, VMW) \
    { \
        if (doStage) STAGE4(st, sbufi); \
        short8 a_[4], b_[4]; \
        _Pragma("unroll") \
        for (int m = 0; m < 4; ++m) \
            a_[m] = *reinterpret_cast<const short8*>(lds + ((bufi) << 14) + ((wr * 4 + m) << 10) + (lane << 4)); \
        _Pragma("unroll") \
        for (int n = 0; n < 4; ++n) \
            b_[n] = *reinterpret_cast<const short8*>(lds + ((bufi) << 14) + ((8 + wc * 4 + n) << 10) + (lane << 4)); \
        __builtin_amdgcn_s_setprio(1); \
        _Pragma("unroll") \
        for (int m = 0; m < 4; ++m) \
            _Pragma("unroll") \
            for (int n = 0; n < 4; ++n) \
                acc[m][n] = __builtin_amdgcn_mfma_f32_16x16x32_bf16(a_[m], b_[n], acc[m][n], 0, 0, 0); \
        __builtin_amdgcn_s_setprio(0); \
        asm volatile("s_waitcnt vmcnt(" #VMW ")" ::: "memory"); \
        __builtin_amdgcn_s_barrier(); \
        SCHED_PIN(); \
    }

    K_TILE(0, 2, true,  2, 4)   // t=0: stage t2->buf2; t1 landed
    K_TILE(1, 0, true,  3, 4)   // t=1: stage t3->buf0; t2 landed
    K_TILE(2, 1, true,  4, 4)
    K_TILE(0, 2, true,  5, 4)
    K_TILE(1, 0, true,  6, 4)
    K_TILE(2, 1, true,  7, 4)
    K_TILE(0, 0, false, 0, 0)   // t=6: no stage; drain t7
    // t=7: last tile, no wait/barrier needed before epilogue's own sync
    {
        short8 a_[4], b_[4];
        #pragma unroll
        for (int m = 0; m < 4; ++m)
            a_[m] = *reinterpret_cast<const short8*>(lds + (1 << 14) + ((wr * 4 + m) << 10) + (lane << 4));
        #pragma unroll
        for (int n = 0; n < 4; ++n)
            b_[n] = *reinterpret_cast<const short8*>(lds + (1 << 14) + ((8 + wc * 4 + n) << 10) + (lane << 4));
        #pragma unroll
        for (int m = 0; m < 4; ++m)
            #pragma unroll
            for (int n = 0; n < 4; ++n)
                acc[m][n] = __builtin_amdgcn_mfma_f32_16x16x32_bf16(a_[m], b_[n], acc[m][n], 0, 0, 0);
    }
    #undef K_TILE

    if (bi == bj) epilogue128<true >(acc, sqA, sqB, caA, cbB, tbl, red, w, lane, wr, wc, partials, blockIdx.x);
    else          epilogue128<false>(acc, sqA, sqB, caA, cbB, tbl, red, w, lane, wr, wc, partials, blockIdx.x);
#endif
}

// ================= fallback: r7-proven 128x128 staged kernel =================
template<bool PRE>
__global__ void pair_kernel(const float* __restrict__ x, const unsigned short* __restrict__ xh,
                            const float* __restrict__ table,
                            const float* __restrict__ sq, const int* __restrict__ ci,
                            int D, int NB, int chunks, int doSwz,
                            double* __restrict__ partials) {
    int bi, bj;
    tri_decode(blockIdx.x, NB, chunks, doSwz, bi, bj);

    __shared__ char ldsbuf[32768];
    __shared__ float sqA[128], sqB[128], tbl[64];
    __shared__ int   caA[128], cbB[128];
    __shared__ float red[12];

    const int tid = threadIdx.x;
    const int w = tid >> 6, lane = tid & 63;
    const int wr = w >> 1, wc = w & 1;
    const int l15 = lane & 15, koct = lane >> 4;

    if (tid < 64) tbl[tid] = table[tid];
    if (tid < 128) { sqA[tid] = sq[bi * 128 + tid]; caA[tid] = ci[bi * 128 + tid]; }
    else { int t2 = tid - 128; sqB[t2] = sq[bj * 128 + t2]; cbB[t2] = ci[bj * 128 + t2]; }
    __syncthreads();

    f32x4 acc[4][4];
    #pragma unroll
    for (int a = 0; a < 4; ++a)
        #pragma unroll
        for (int b = 0; b < 4; ++b) acc[a][b] = (f32x4){0.f, 0.f, 0.f, 0.f};

    const size_t aoff = (size_t)(bi * 128 + wr * 64 + l15) * D + koct * 8;
    const size_t boff = (size_t)(bj * 128 + wc * 64 + l15) * D + koct * 8;

    bool staged = false;
#if HAVE_GLL
    if (PRE && ((D & 63) == 0)) {
        staged = true;
        const unsigned short* gpan = (w >= 2) ? (xh + (size_t)bj * 128 * D)
                                              : (xh + (size_t)bi * 128 * D);
        const int kcw = w & 1;
        char* ldsw = ldsbuf + ((w >= 2) ? 16384 : 0) + kcw * 8192;
        const size_t gk = (size_t)(kcw * 32 + koct * 8) + (size_t)l15 * D;
        auto STAGE = [&](int ks) {
            const unsigned short* g0 = gpan + gk + ks * 64;
            #pragma unroll
            for (int i = 0; i < 8; ++i) {
                __builtin_amdgcn_global_load_lds(
                    (__attribute__((address_space(1))) void*)(void*)(g0 + (size_t)i * 16 * D),
                    (__attribute__((address_space(3))) void*)(ldsw + i * 1024),
                    16, 0, 0);
            }
        };
        const int nks = D >> 6;
        STAGE(0);
        for (int ks = 0; ks < nks; ++ks) {
            __syncthreads();
            #pragma unroll
            for (int kc = 0; kc < 2; ++kc) {
                short8 a[4], b[4];
                #pragma unroll
                for (int m = 0; m < 4; ++m)
                    a[m] = *reinterpret_cast<const short8*>(ldsbuf + (kc * 8 + wr * 4 + m) * 1024 + lane * 16);
                #pragma unroll
                for (int n = 0; n < 4; ++n)
                    b[n] = *reinterpret_cast<const short8*>(ldsbuf + 16384 + (kc * 8 + wc * 4 + n) * 1024 + lane * 16);
                #pragma unroll
                for (int fm = 0; fm < 4; ++fm)
                    #pragma unroll
                    for (int fn = 0; fn < 4; ++fn)
                        acc[fm][fn] = __builtin_amdgcn_mfma_f32_16x16x32_bf16(a[fm], b[fn], acc[fm][fn], 0, 0, 0);
            }
            if (ks + 1 < nks) { __syncthreads(); STAGE(ks + 1); }
        }
    }
#endif
    if (!staged) {
        const float* pa = x + aoff;
        const unsigned short* ha = xh + aoff;
        const float* pb = x + boff;
        const unsigned short* hb = xh + boff;
        const size_t rs = (size_t)16 * D;
        for (int k = 0; k < D; k += 32) {
            short8 af[4], bfv[4];
            if (PRE) {
                #pragma unroll
                for (int m = 0; m < 4; ++m) af[m]  = *reinterpret_cast<const short8*>(ha + m * rs + k);
                #pragma unroll
                for (int n = 0; n < 4; ++n) bfv[n] = *reinterpret_cast<const short8*>(hb + n * rs + k);
            } else {
                #pragma unroll
                for (int m = 0; m < 4; ++m) {
                    float4 f0 = *reinterpret_cast<const float4*>(pa + m * rs + k);
                    float4 f1 = *reinterpret_cast<const float4*>(pa + m * rs + k + 4);
                    short8 v;
                    v[0]=(short)f2bf(f0.x); v[1]=(short)f2bf(f0.y); v[2]=(short)f2bf(f0.z); v[3]=(short)f2bf(f0.w);
                    v[4]=(short)f2bf(f1.x); v[5]=(short)f2bf(f1.y); v[6]=(short)f2bf(f1.z); v[7]=(short)f2bf(f1.w);
                    af[m] = v;
                }
                #pragma unroll
                for (int n = 0; n < 4; ++n) {
                    float4 f0 = *reinterpret_cast<const float4*>(pb + n * rs + k);
                    float4 f1 = *reinterpret_cast<const float4*>(pb + n * rs + k + 4);
                    short8 v;
                    v[0]=(short)f2bf(f0.x); v[1]=(short)f2bf(f0.y); v[2]=(short)f2bf(f0.z); v[3]=(short)f2bf(f0.w);
                    v[4]=(short)f2bf(f1.x); v[5]=(short)f2bf(f1.y); v[6]=(short)f2bf(f1.z); v[7]=(short)f2bf(f1.w);
                    bfv[n] = v;
                }
            }
            #pragma unroll
            for (int fm = 0; fm < 4; ++fm)
                #pragma unroll
                for (int fn = 0; fn < 4; ++fn)
                    acc[fm][fn] = __builtin_amdgcn_mfma_f32_16x16x32_bf16(af[fm], bfv[fn], acc[fm][fn], 0, 0, 0);
        }
    }

    if (bi == bj) epilogue128<true >(acc, sqA, sqB, caA, cbB, tbl, red, w, lane, wr, wc, partials, blockIdx.x);
    else          epilogue128<false>(acc, sqA, sqB, caA, cbB, tbl, red, w, lane, wr, wc, partials, blockIdx.x);
}

__global__ void finalize_kernel(const double* __restrict__ partials, int nL,
                                const int* __restrict__ civ, int N,
                                const float* __restrict__ table, int tdim,
                                float* __restrict__ out) {
    __shared__ unsigned int h[64];
    __shared__ double red[4][5];
    const int tid = threadIdx.x;     // 256 threads
    if (tid < 64) h[tid] = 0u;
    __syncthreads();
    for (int i = tid; i < N; i += 256) atomicAdd(&h[civ[i]], 1u);   // LDS histogram
    __syncthreads();

    double se = 0, sd2 = 0, setv = 0;
    for (int i = tid; i < nL; i += 256) {
        const double* p = partials + (size_t)i * 4;
        se += p[0]; sd2 += p[1]; setv += p[2];
    }
    double st = 0, stt = 0;
    for (int c = tid; c < 4096; c += 256) {
        int u = c >> 6, v = c & 63;
        double t = (double)table[u * tdim + v];
        double hh = (double)h[u] * (double)h[v];
        st += hh * t; stt += hh * t * t;
    }
    #pragma unroll
    for (int o = 32; o > 0; o >>= 1) {
        se += __shfl_down(se, o, 64);
        sd2 += __shfl_down(sd2, o, 64);
        setv += __shfl_down(setv, o, 64);
        st += __shfl_down(st, o, 64);
        stt += __shfl_down(stt, o, 64);
    }
    int w = tid >> 6;
    if ((tid & 63) == 0) { red[w][0] = se; red[w][1] = sd2; red[w][2] = setv; red[w][3] = st; red[w][4] = stt; }
    __syncthreads();
    if (tid == 0) {
        double S[5] = {0, 0, 0, 0, 0};
        #pragma unroll
        for (int i = 0; i < 4; ++i)
            #pragma unroll
            for (int q = 0; q < 5; ++q) S[q] += red[i][q];
        double nn = (double)N * (double)N;
        // Pearson corr is scale-invariant: the /(max+eps) normalization is a no-op
        double cet = S[2] - S[0] * S[3] / nn;
        double cee = S[1] - S[0] * S[0] / nn;
        double ctt = S[4] - S[3] * S[3] / nn;
        double corr = cet / (sqrt(cee * ctt) + 1e-10);
        out[0] = (float)(1.0 - corr);
    }
}

extern "C" void kernel_launch(void* const* d_in, const int* in_sizes, int n_in,
                              void* d_out, int out_size, void* d_ws, size_t ws_size,
                              hipStream_t stream) {
    const float* x     = (const float*)d_in[0];
    const int*   idx   = (const int*)d_in[1];
    const float* table = (const float*)d_in[2];

    const int N = in_sizes[1];              // 8192
    const int D = in_sizes[0] / N;          // 256
    int tdim = 1;
    while (tdim * tdim < in_sizes[2]) ++tdim;   // 81

    char* ws = (char*)d_ws;
    double*         partials = (double*)(ws + 512);
    float*          sqv      = (float*)(ws + 67584);
    int*            civ      = (int*)(ws + 67584 + (size_t)N * 4);
    unsigned short* xh       = (unsigned short*)(ws + 67584 + (size_t)N * 8);

    size_t need = 67584 + (size_t)N * 8 + (size_t)N * D * 2;
    const bool pre = (ws_size >= need);

    rowstats_kernel<<<dim3(512), 256, 0, stream>>>(x, idx, sqv, civ, xh, N, D, pre ? 1 : 0);

    const int NB = N / 128;
    const int nL = NB * (NB + 1) / 2;            // 2080
    const int doSwz = (nL % 8 == 0) ? 1 : 0;
    const int chunks = nL / 8;

    // host-side gate must not reference HAVE_GLL (0 in host pass — r9/r10 bug)
    if (pre && D == 256 && (N % 128 == 0))
        pair128p_kernel<<<dim3(nL), 256, 0, stream>>>(xh, table, sqv, civ, NB, chunks, doSwz, partials);
    else if (pre)
        pair_kernel<true><<<dim3(nL), 256, 0, stream>>>(x, xh, table, sqv, civ, D, NB, chunks, doSwz, partials);
    else
        pair_kernel<false><<<dim3(nL), 256, 0, stream>>>(x, xh, table, sqv, civ, D, NB, chunks, doSwz, partials);

    finalize_kernel<<<1, 256, 0, stream>>>(partials, nL, civ, N, table, tdim, (float*)d_out);
}